// Round 1
// baseline (1586.438 us; speedup 1.0000x reference)
//
#include <hip/hip_runtime.h>
#include <hip/hip_bf16.h>
#include <math.h>

#define B 2
#define N 2048
#define C 1024
#define H 16
#define D 64
#define TC 3072            // 3*C
#define BNROWS (B*N)       // 4096
#define LN_EPS 1e-5f

// ---------------- GEMM: out = A(MxK) * W(NoutxK)^T ----------------
// MODE 0: scatter into qkv buffer laid out [3][B][H][N][D]
// MODE 1: linear out (M x Nout) + bias
#define BM 64
#define BNT 64
#define BK 16

template <int MODE>
__global__ __launch_bounds__(256) void gemm_kernel(
    const float* __restrict__ A, const float* __restrict__ W,
    float* __restrict__ out, const float* __restrict__ bias, int K)
{
    __shared__ float As[BK][BM + 1];
    __shared__ float Ws[BK][BNT + 1];
    const int tid = threadIdx.x;
    const int tx = tid & 15, ty = tid >> 4;
    const int row0 = blockIdx.y * BM;
    const int col0 = blockIdx.x * BNT;

    float acc[4][4] = {};

    const int m = tid >> 2;            // 0..63
    const int kk0 = (tid & 3) * 4;     // 0,4,8,12

    for (int k0 = 0; k0 < K; k0 += BK) {
        const float4 av = *reinterpret_cast<const float4*>(&A[(size_t)(row0 + m) * K + k0 + kk0]);
        As[kk0 + 0][m] = av.x; As[kk0 + 1][m] = av.y; As[kk0 + 2][m] = av.z; As[kk0 + 3][m] = av.w;
        const float4 wv = *reinterpret_cast<const float4*>(&W[(size_t)(col0 + m) * K + k0 + kk0]);
        Ws[kk0 + 0][m] = wv.x; Ws[kk0 + 1][m] = wv.y; Ws[kk0 + 2][m] = wv.z; Ws[kk0 + 3][m] = wv.w;
        __syncthreads();
        #pragma unroll
        for (int kk = 0; kk < BK; ++kk) {
            float a[4], b[4];
            #pragma unroll
            for (int i = 0; i < 4; ++i) a[i] = As[kk][ty * 4 + i];
            #pragma unroll
            for (int j = 0; j < 4; ++j) b[j] = Ws[kk][tx * 4 + j];
            #pragma unroll
            for (int i = 0; i < 4; ++i)
                #pragma unroll
                for (int j = 0; j < 4; ++j)
                    acc[i][j] = fmaf(a[i], b[j], acc[i][j]);
        }
        __syncthreads();
    }

    #pragma unroll
    for (int i = 0; i < 4; ++i) {
        const int row = row0 + ty * 4 + i;
        #pragma unroll
        for (int j = 0; j < 4; ++j) {
            const int col = col0 + tx * 4 + j;
            if (MODE == 0) {
                // row = b*N + n ; col = which*1024 + h*64 + d
                const int b = row >> 11;          // /N
                const int n = row & (N - 1);
                const int which = col >> 10;
                const int h = (col >> 6) & (H - 1);
                const int d = col & (D - 1);
                const size_t plane = ((size_t)(which * B + b) * H + h) * ((size_t)N * D);
                out[plane + (size_t)n * D + d] = acc[i][j];
            } else {
                out[(size_t)row * C + col] = acc[i][j] + bias[col];
            }
        }
    }
}

// ---------------- fused LayerNorm(D=64) + RoPE on q,k rows ----------------
__global__ __launch_bounds__(256) void lnrope_kernel(
    float* __restrict__ qkv, const float* __restrict__ qw, const float* __restrict__ qb,
    const float* __restrict__ kw, const float* __restrict__ kb, const int* __restrict__ pos)
{
    const int tid = threadIdx.x;
    const int lane = tid & 63;
    const int row = blockIdx.x * 4 + (tid >> 6);      // [0, 2*B*H*N)
    const int isK = row >= (B * H * N);
    const float* w = isK ? kw : qw;
    const float* bb = isK ? kb : qb;
    float* rowp = qkv + (size_t)row * D;

    float v = rowp[lane];
    float s = v;
    #pragma unroll
    for (int msk = 32; msk >= 1; msk >>= 1) s += __shfl_xor(s, msk, 64);
    const float mu = s * (1.0f / 64.0f);
    const float dv = v - mu;
    float s2 = dv * dv;
    #pragma unroll
    for (int msk = 32; msk >= 1; msk >>= 1) s2 += __shfl_xor(s2, msk, 64);
    const float var = s2 * (1.0f / 64.0f);
    float y = dv * rsqrtf(var + LN_EPS) * w[lane] + bb[lane];

    // RoPE
    const int n = row & (N - 1);
    const int d2 = lane & 31;
    const float inv_freq = 1.0f / powf(10000.0f, (float)d2 * (1.0f / 32.0f));
    const float ang = (float)pos[n] * inv_freq;
    const float c = cosf(ang), sn = sinf(ang);
    const float partner = __shfl_xor(y, 32, 64);
    float outv;
    if (lane < 32) outv = y * c - partner * sn;   // x1*cos - x2*sin
    else           outv = partner * sn + y * c;   // x1*sin + x2*cos
    rowp[lane] = outv;
}

// ---------------- flash-style attention, fp32 ----------------
// grid: B*H*(N/64) blocks of 256 threads; each block: 64 q-rows
__global__ __launch_bounds__(256) void attn_kernel(
    const float* __restrict__ qkv, float* __restrict__ attnOut)
{
    __shared__ float Qs[64][D + 1];
    __shared__ float Ks[64][D + 1];
    __shared__ float Vs[64][D + 1];
    __shared__ float Ps[64][64 + 1];

    const int tid = threadIdx.x;
    const int tx = tid & 15, ty = tid >> 4;
    const int qt = blockIdx.x & 31;
    const int h = (blockIdx.x >> 5) & (H - 1);
    const int b = blockIdx.x >> 9;

    const size_t plane = (size_t)N * D;
    const float* Qg = qkv + ((size_t)(0 * B + b) * H + h) * plane + (size_t)qt * 64 * D;
    const float* Kg = qkv + ((size_t)(1 * B + b) * H + h) * plane;
    const float* Vg = qkv + ((size_t)(2 * B + b) * H + h) * plane;

    for (int e = tid; e < 64 * D; e += 256) {
        const int r = e >> 6, d = e & 63;
        Qs[r][d] = Qg[(size_t)r * D + d] * 0.125f;   // scale = D^-0.5
    }

    float o[4][4] = {};
    float mrow[4], lrow[4];
    #pragma unroll
    for (int i = 0; i < 4; ++i) { mrow[i] = -1e30f; lrow[i] = 0.0f; }

    for (int kt = 0; kt < N / 64; ++kt) {
        __syncthreads();
        for (int e = tid; e < 64 * D; e += 256) {
            const int r = e >> 6, d = e & 63;
            Ks[r][d] = Kg[(size_t)(kt * 64 + r) * D + d];
            Vs[r][d] = Vg[(size_t)(kt * 64 + r) * D + d];
        }
        __syncthreads();

        // S = Q * K^T  (4x4 per thread)
        float sacc[4][4] = {};
        #pragma unroll 8
        for (int dd = 0; dd < D; ++dd) {
            float a[4], bb[4];
            #pragma unroll
            for (int i = 0; i < 4; ++i) a[i] = Qs[ty * 4 + i][dd];
            #pragma unroll
            for (int j = 0; j < 4; ++j) bb[j] = Ks[tx * 4 + j][dd];
            #pragma unroll
            for (int i = 0; i < 4; ++i)
                #pragma unroll
                for (int j = 0; j < 4; ++j)
                    sacc[i][j] = fmaf(a[i], bb[j], sacc[i][j]);
        }

        // online softmax; 16 lanes (same ty) share each q-row
        #pragma unroll
        for (int i = 0; i < 4; ++i) {
            float pm = fmaxf(fmaxf(sacc[i][0], sacc[i][1]), fmaxf(sacc[i][2], sacc[i][3]));
            #pragma unroll
            for (int msk = 8; msk >= 1; msk >>= 1) pm = fmaxf(pm, __shfl_xor(pm, msk, 64));
            const float newm = fmaxf(mrow[i], pm);
            const float f = __expf(mrow[i] - newm);
            float ps = 0.0f;
            #pragma unroll
            for (int j = 0; j < 4; ++j) {
                const float p = __expf(sacc[i][j] - newm);
                Ps[ty * 4 + i][tx * 4 + j] = p;
                ps += p;
            }
            #pragma unroll
            for (int msk = 8; msk >= 1; msk >>= 1) ps += __shfl_xor(ps, msk, 64);
            lrow[i] = lrow[i] * f + ps;
            mrow[i] = newm;
            #pragma unroll
            for (int j = 0; j < 4; ++j) o[i][j] *= f;
        }
        __syncthreads();

        // O += P * V
        #pragma unroll 8
        for (int kk = 0; kk < 64; ++kk) {
            float a[4], bb[4];
            #pragma unroll
            for (int i = 0; i < 4; ++i) a[i] = Ps[ty * 4 + i][kk];
            #pragma unroll
            for (int j = 0; j < 4; ++j) bb[j] = Vs[kk][tx * 4 + j];
            #pragma unroll
            for (int i = 0; i < 4; ++i)
                #pragma unroll
                for (int j = 0; j < 4; ++j)
                    o[i][j] = fmaf(a[i], bb[j], o[i][j]);
        }
    }

    #pragma unroll
    for (int i = 0; i < 4; ++i) {
        const int n = qt * 64 + ty * 4 + i;
        const float inv_l = 1.0f / lrow[i];
        #pragma unroll
        for (int j = 0; j < 4; ++j) {
            attnOut[((size_t)b * N + n) * C + h * 64 + tx * 4 + j] = o[i][j] * inv_l;
        }
    }
}

extern "C" void kernel_launch(void* const* d_in, const int* in_sizes, int n_in,
                              void* d_out, int out_size, void* d_ws, size_t ws_size,
                              hipStream_t stream) {
    const float* x      = (const float*)d_in[0];
    const float* qkv_w  = (const float*)d_in[1];
    const float* qn_w   = (const float*)d_in[2];
    const float* qn_b   = (const float*)d_in[3];
    const float* kn_w   = (const float*)d_in[4];
    const float* kn_b   = (const float*)d_in[5];
    const float* proj_w = (const float*)d_in[6];
    const float* proj_b = (const float*)d_in[7];
    const int*   pos    = (const int*)d_in[8];
    float* out = (float*)d_out;

    float* qkvBuf  = (float*)d_ws;                       // [3][B][H][N][D] = 50.3 MB
    float* attnOut = qkvBuf + (size_t)3 * B * H * N * D; // [B][N][C] = 16.8 MB

    dim3 blk(256);
    // 1) QKV GEMM (scatter into [3][B][H][N][D])
    gemm_kernel<0><<<dim3(TC / BNT, BNROWS / BM), blk, 0, stream>>>(x, qkv_w, qkvBuf, nullptr, C);
    // 2) LayerNorm + RoPE on q,k
    lnrope_kernel<<<dim3(2 * B * H * N / 4), blk, 0, stream>>>(qkvBuf, qn_w, qn_b, kn_w, kn_b, pos);
    // 3) attention
    attn_kernel<<<dim3(B * H * (N / 64)), blk, 0, stream>>>(qkvBuf, attnOut);
    // 4) proj GEMM + bias
    gemm_kernel<1><<<dim3(C / BNT, BNROWS / BM), blk, 0, stream>>>(attnOut, proj_w, out, proj_b, C);
}

// Round 2
// 202.979 us; speedup vs baseline: 7.8158x; 7.8158x over previous
//
#include <hip/hip_runtime.h>
#include <hip/hip_bf16.h>
#include <math.h>
#include <stdint.h>

#define B 2
#define N 2048
#define C 1024
#define H 16
#define D 64
#define LN_EPS 1e-5f

typedef unsigned short u16;
typedef unsigned int u32;
typedef __attribute__((ext_vector_type(8))) short b16x8;
typedef __attribute__((ext_vector_type(4))) float f32x4;

#define MFMA(a, b, c) __builtin_amdgcn_mfma_f32_16x16x32_bf16(a, b, c, 0, 0, 0)

__device__ __forceinline__ u16 f2bf(float x) {
    u32 u = __float_as_uint(x);
    u32 r = u + 0x7fff + ((u >> 16) & 1);   // RNE
    return (u16)(r >> 16);
}
__device__ __forceinline__ float bf2f(u16 v) {
    return __uint_as_float(((u32)v) << 16);
}
__device__ __forceinline__ void gload_lds16(const void* g, void* l) {
    __builtin_amdgcn_global_load_lds(
        (__attribute__((address_space(1))) void*)(uintptr_t)g,
        (__attribute__((address_space(3))) void*)l, 16, 0, 0);
}

// ---------------- cast fp32 -> bf16 (vectorized) ----------------
__global__ __launch_bounds__(256) void castk(const float* __restrict__ in,
                                             u16* __restrict__ out, int n4) {
    int i = blockIdx.x * 256 + threadIdx.x;
    if (i < n4) {
        float4 v = ((const float4*)in)[i];
        ushort4 o;
        o.x = f2bf(v.x); o.y = f2bf(v.y); o.z = f2bf(v.z); o.w = f2bf(v.w);
        ((ushort4*)out)[i] = o;
    }
}

// ---------------- bf16 MFMA GEMM: out = A(MxK) * W(NoutxK)^T ----------------
// 128x128 tile, BK=32, 4 waves (2x2), per-wave 64x64 (4x4 frags of 16x16).
// MODE 0: scatter q,k -> qkb [2][B][H][N][D] bf16 ; v -> vbuf [B][H][N][D] bf16
// MODE 1: fp32 out (M x C) + bias
template <int MODE>
__global__ __launch_bounds__(256) void mfma_gemm(
    const u16* __restrict__ A, const u16* __restrict__ W,
    float* __restrict__ outp, const float* __restrict__ bias,
    u16* __restrict__ qkb, u16* __restrict__ vbuf, int K)
{
    __shared__ u16 As[128 * 32];
    __shared__ u16 Ws[128 * 32];
    const int tid = threadIdx.x;
    const int lane = tid & 63, wave = tid >> 6;
    const int g = lane >> 4, c = lane & 15;
    const int wr = wave >> 1, wc = wave & 1;
    const int row0 = blockIdx.y * 128, col0 = blockIdx.x * 128;

    f32x4 acc[4][4];
    #pragma unroll
    for (int m = 0; m < 4; ++m)
        #pragma unroll
        for (int n = 0; n < 4; ++n) acc[m][n] = (f32x4){0.f, 0.f, 0.f, 0.f};

    for (int k0 = 0; k0 < K; k0 += 32) {
        __syncthreads();
        #pragma unroll
        for (int rep = 0; rep < 2; ++rep) {
            const int idx = rep * 256 + tid;
            const int r_ = idx >> 2, ch = idx & 3;      // row 0..127, 16B chunk 0..3
            gload_lds16(A + (size_t)(row0 + r_) * K + k0 + ch * 8,
                        As + rep * 2048 + wave * 512);
            gload_lds16(W + (size_t)(col0 + r_) * K + k0 + ch * 8,
                        Ws + rep * 2048 + wave * 512);
        }
        __syncthreads();

        b16x8 af[4], wf[4];
        #pragma unroll
        for (int m = 0; m < 4; ++m)
            af[m] = *(const b16x8*)&As[(wr * 64 + m * 16 + c) * 32 + g * 8];
        #pragma unroll
        for (int n = 0; n < 4; ++n)
            wf[n] = *(const b16x8*)&Ws[(wc * 64 + n * 16 + c) * 32 + g * 8];
        #pragma unroll
        for (int m = 0; m < 4; ++m)
            #pragma unroll
            for (int n = 0; n < 4; ++n)
                acc[m][n] = MFMA(af[m], wf[n], acc[m][n]);
    }

    #pragma unroll
    for (int m = 0; m < 4; ++m)
        #pragma unroll
        for (int n = 0; n < 4; ++n)
            #pragma unroll
            for (int r = 0; r < 4; ++r) {
                const int row = row0 + wr * 64 + m * 16 + g * 4 + r;   // D row = 4g+reg
                const int col = col0 + wc * 64 + n * 16 + c;           // D col = lane&15
                const float v = acc[m][n][r];
                if (MODE == 0) {
                    const int which = col >> 10, hd = col & 1023;
                    const int hh = hd >> 6, dd = hd & 63;
                    const int bb = row >> 11, nn = row & (N - 1);
                    if (which < 2)
                        qkb[(size_t)which * (B * H * N * D) +
                            (((size_t)(bb * H + hh)) * N + nn) * 64 + dd] = f2bf(v);
                    else
                        vbuf[(((size_t)(bb * H + hh)) * N + nn) * 64 + dd] = f2bf(v);
                } else {
                    outp[(size_t)row * C + col] = v + bias[col];
                }
            }
}

// ---------------- fused LayerNorm(D=64) + RoPE on q,k rows (bf16 io) -------
// Q additionally pre-scaled by 2^-3 (= D^-0.5, exact in bf16)
__global__ __launch_bounds__(256) void lnrope_kernel(
    u16* __restrict__ qkv, const float* __restrict__ qw, const float* __restrict__ qb,
    const float* __restrict__ kw, const float* __restrict__ kb, const int* __restrict__ pos)
{
    const int tid = threadIdx.x;
    const int lane = tid & 63;
    const int row = blockIdx.x * 4 + (tid >> 6);      // [0, 2*B*H*N)
    const int isK = row >= (B * H * N);
    const float* w = isK ? kw : qw;
    const float* bb = isK ? kb : qb;
    u16* rowp = qkv + (size_t)row * D;

    float v = bf2f(rowp[lane]);
    float s = v;
    #pragma unroll
    for (int msk = 32; msk >= 1; msk >>= 1) s += __shfl_xor(s, msk, 64);
    const float mu = s * (1.0f / 64.0f);
    const float dv = v - mu;
    float s2 = dv * dv;
    #pragma unroll
    for (int msk = 32; msk >= 1; msk >>= 1) s2 += __shfl_xor(s2, msk, 64);
    const float var = s2 * (1.0f / 64.0f);
    float y = dv * rsqrtf(var + LN_EPS) * w[lane] + bb[lane];

    const int n = row & (N - 1);
    const int d2 = lane & 31;
    const float inv_freq = 1.0f / powf(10000.0f, (float)d2 * (1.0f / 32.0f));
    const float ang = (float)pos[n] * inv_freq;
    const float cc = cosf(ang), sn = sinf(ang);
    const float partner = __shfl_xor(y, 32, 64);
    float outv;
    if (lane < 32) outv = y * cc - partner * sn;
    else           outv = partner * sn + y * cc;
    if (!isK) outv *= 0.125f;                 // fold q scale (exact pow2)
    rowp[lane] = f2bf(outv);
}

// ---------------- attention: bf16 MFMA, swapped QK^T (S^T), online softmax --
// block = 256 thr = 4 waves; each wave 16 q rows; KV tiles of 64.
__global__ __launch_bounds__(256) void attn_kernel(
    const u16* __restrict__ qkb, const u16* __restrict__ vb, u16* __restrict__ aout)
{
    __shared__ u16 Kl[64 * 64];   // [j][d], d 16B-chunk XOR-swizzled by (j&7)
    __shared__ u16 Vt[64 * 64];   // [d][j], j XOR-swizzled by ((d&7)<<3)
    const int tid = threadIdx.x, lane = tid & 63, wave = tid >> 6;
    const int g = lane >> 4, c = lane & 15;
    const int qt = blockIdx.x & 31, h = (blockIdx.x >> 5) & (H - 1), b = blockIdx.x >> 9;
    const size_t headbase = ((size_t)(b * H + h)) * N * D;
    const u16* Qg = qkb + headbase;                      // plane 0 (pre-scaled)
    const u16* Kg = qkb + (size_t)B * H * N * D + headbase;
    const u16* Vg = vb + headbase;
    const int q0 = qt * 64 + wave * 16;

    // Q fragments (B-operand of S^T): lane c supplies col q0+c, k=d
    b16x8 qf[2];
    #pragma unroll
    for (int ks = 0; ks < 2; ++ks)
        qf[ks] = *(const b16x8*)&Qg[(size_t)(q0 + c) * 64 + ks * 32 + g * 8];

    f32x4 oacc[4];
    #pragma unroll
    for (int nd = 0; nd < 4; ++nd) oacc[nd] = (f32x4){0.f, 0.f, 0.f, 0.f};
    float m_run = -1e30f, l_run = 0.f;

    const int jp = (tid & 31) * 2, dg = tid >> 5;   // V staging assignment

    for (int kt = 0; kt < N / 64; ++kt) {
        __syncthreads();
        // --- K tile -> LDS via global_load_lds, source pre-swizzled ---
        #pragma unroll
        for (int rep = 0; rep < 2; ++rep) {
            const int idx = rep * 256 + tid;
            const int j = idx >> 3, ccc = idx & 7;
            const int cg = ccc ^ (j & 7);
            gload_lds16(Kg + (size_t)(kt * 64 + j) * 64 + cg * 8,
                        Kl + rep * 2048 + wave * 512);
        }
        // --- V tile -> LDS transposed + swizzled (reg staging) ---
        {
            const b16x8 va = *(const b16x8*)&Vg[(size_t)(kt * 64 + jp) * 64 + dg * 8];
            const b16x8 vbv = *(const b16x8*)&Vg[(size_t)(kt * 64 + jp + 1) * 64 + dg * 8];
            #pragma unroll
            for (int dd = 0; dd < 8; ++dd) {
                const int d = dg * 8 + dd;
                const int slot = jp ^ ((d & 7) << 3);
                const u32 pk = (u32)(u16)va[dd] | ((u32)(u16)vbv[dd] << 16);
                *(u32*)&Vt[d * 64 + slot] = pk;
            }
        }
        __syncthreads();

        // --- S^T = K * Q^T : rows j (4 frags), cols q (16) ---
        f32x4 sac[4];
        #pragma unroll
        for (int jt = 0; jt < 4; ++jt) sac[jt] = (f32x4){0.f, 0.f, 0.f, 0.f};
        #pragma unroll
        for (int jt = 0; jt < 4; ++jt)
            #pragma unroll
            for (int ks = 0; ks < 2; ++ks) {
                const int byteoff = (jt * 16 + c) * 128 + ((ks * 64 + g * 16) ^ ((c & 7) << 4));
                const b16x8 kf = *(const b16x8*)((const char*)Kl + byteoff);
                sac[jt] = MFMA(kf, qf[ks], sac[jt]);
            }

        // --- online softmax: lane holds 16 S values for q = c, j = jt*16+4g+r ---
        float pm = -1e30f;
        #pragma unroll
        for (int jt = 0; jt < 4; ++jt)
            #pragma unroll
            for (int r = 0; r < 4; ++r) pm = fmaxf(pm, sac[jt][r]);
        pm = fmaxf(pm, __shfl_xor(pm, 16, 64));
        pm = fmaxf(pm, __shfl_xor(pm, 32, 64));
        const float mnew = fmaxf(m_run, pm);
        const float fs = __expf(m_run - mnew);
        float ps = 0.f;
        #pragma unroll
        for (int jt = 0; jt < 4; ++jt)
            #pragma unroll
            for (int r = 0; r < 4; ++r) {
                const float pv = __expf(sac[jt][r] - mnew);
                sac[jt][r] = pv;
                ps += pv;
            }
        ps += __shfl_xor(ps, 16, 64);
        ps += __shfl_xor(ps, 32, 64);
        l_run = l_run * fs + ps;
        m_run = mnew;
        #pragma unroll
        for (int r = 0; r < 4; ++r) {
            const float fr = __shfl(fs, (lane & 48) + g * 4 + r, 64);
            #pragma unroll
            for (int nd = 0; nd < 4; ++nd) oacc[nd][r] *= fr;
        }

        // --- P fragments (A-operand of PV), pure lane-local repack ---
        b16x8 paf[2];
        #pragma unroll
        for (int ks = 0; ks < 2; ++ks)
            #pragma unroll
            for (int i = 0; i < 8; ++i)
                paf[ks][i] = (short)f2bf(sac[ks * 2 + (i >> 2)][i & 3]);

        // --- O += P * V : V^T from swizzled LDS ---
        #pragma unroll
        for (int nd = 0; nd < 4; ++nd) {
            const int d = nd * 16 + c;
            const int rowb = d * 64;
            const int X = (c & 7) << 3;
            #pragma unroll
            for (int ks = 0; ks < 2; ++ks) {
                const int j0a = (ks * 2) * 16 + g * 4;
                const int j0b = (ks * 2 + 1) * 16 + g * 4;
                const ushort4 xa = *(const ushort4*)&Vt[rowb + (j0a ^ X)];
                const ushort4 xb2 = *(const ushort4*)&Vt[rowb + (j0b ^ X)];
                const b16x8 vf = {(short)xa.x, (short)xa.y, (short)xa.z, (short)xa.w,
                                  (short)xb2.x, (short)xb2.y, (short)xb2.z, (short)xb2.w};
                oacc[nd] = MFMA(paf[ks], vf, oacc[nd]);
            }
        }
    }

    // --- epilogue: scale by 1/l, write bf16 [b][n][h*64+d] ---
    const float linv = 1.0f / l_run;
    #pragma unroll
    for (int r = 0; r < 4; ++r) {
        const float li = __shfl(linv, (lane & 48) + g * 4 + r, 64);
        const int n_ = q0 + g * 4 + r;
        #pragma unroll
        for (int nd = 0; nd < 4; ++nd)
            aout[((size_t)(b * N + n_)) * C + h * 64 + nd * 16 + c] =
                f2bf(oacc[nd][r] * li);
    }
}

extern "C" void kernel_launch(void* const* d_in, const int* in_sizes, int n_in,
                              void* d_out, int out_size, void* d_ws, size_t ws_size,
                              hipStream_t stream) {
    const float* x      = (const float*)d_in[0];
    const float* qkv_w  = (const float*)d_in[1];
    const float* qn_w   = (const float*)d_in[2];
    const float* qn_b   = (const float*)d_in[3];
    const float* kn_w   = (const float*)d_in[4];
    const float* kn_b   = (const float*)d_in[5];
    const float* proj_w = (const float*)d_in[6];
    const float* proj_b = (const float*)d_in[7];
    const int*   pos    = (const int*)d_in[8];
    float* out = (float*)d_out;

    u16* xb     = (u16*)d_ws;                 // 4096x1024
    u16* wqkvb  = xb + 4194304;               // 3072x1024
    u16* wprojb = wqkvb + 3145728;            // 1024x1024
    u16* qkb    = wprojb + 1048576;           // [2][B][H][N][D]
    u16* vbuf   = qkb + 8388608;              // [B][H][N][D]
    u16* aob    = vbuf + 4194304;             // [B][N][C]

    castk<<<4096, 256, 0, stream>>>(x, xb, 1048576);
    castk<<<3072, 256, 0, stream>>>(qkv_w, wqkvb, 786432);
    castk<<<1024, 256, 0, stream>>>(proj_w, wprojb, 262144);

    mfma_gemm<0><<<dim3(24, 32), 256, 0, stream>>>(xb, wqkvb, nullptr, nullptr, qkb, vbuf, C);
    lnrope_kernel<<<32768, 256, 0, stream>>>(qkb, qn_w, qn_b, kn_w, kn_b, pos);
    attn_kernel<<<dim3(B * H * (N / 64)), 256, 0, stream>>>(qkb, vbuf, aob);
    mfma_gemm<1><<<dim3(8, 32), 256, 0, stream>>>(aob, wprojb, out, proj_b, nullptr, nullptr, C);
}

// Round 3
// 178.939 us; speedup vs baseline: 8.8658x; 1.1343x over previous
//
#include <hip/hip_runtime.h>
#include <hip/hip_bf16.h>
#include <math.h>
#include <stdint.h>

#define B 2
#define N 2048
#define C 1024
#define H 16
#define D 64
#define LN_EPS 1e-5f

typedef unsigned short u16;
typedef unsigned int u32;
typedef __attribute__((ext_vector_type(8))) short b16x8;
typedef __attribute__((ext_vector_type(4))) float f32x4;

#define MFMA(a, b, c) __builtin_amdgcn_mfma_f32_16x16x32_bf16(a, b, c, 0, 0, 0)

__device__ __forceinline__ u16 f2bf(float x) {
    u32 u = __float_as_uint(x);
    u32 r = u + 0x7fff + ((u >> 16) & 1);   // RNE
    return (u16)(r >> 16);
}
__device__ __forceinline__ float bf2f(u16 v) {
    return __uint_as_float(((u32)v) << 16);
}
__device__ __forceinline__ void gload_lds16(const void* g, void* l) {
    __builtin_amdgcn_global_load_lds(
        (__attribute__((address_space(1))) void*)(uintptr_t)g,
        (__attribute__((address_space(3))) void*)l, 16, 0, 0);
}
__device__ __forceinline__ float exp2_asm(float x) {
    float r;
    asm("v_exp_f32 %0, %1" : "=v"(r) : "v"(x));
    return r;
}
__device__ __forceinline__ u32 cvtpk_bf16(float lo, float hi) {
    u32 r;
    asm("v_cvt_pk_bf16_f32 %0, %1, %2" : "=v"(r) : "v"(lo), "v"(hi));
    return r;
}

union PW { u32 w[4]; b16x8 v; };

// ---------------- cast fp32 -> bf16 (vectorized) ----------------
__global__ __launch_bounds__(256) void castk(const float* __restrict__ in,
                                             u16* __restrict__ out, int n4) {
    int i = blockIdx.x * 256 + threadIdx.x;
    if (i < n4) {
        float4 v = ((const float4*)in)[i];
        ushort4 o;
        o.x = f2bf(v.x); o.y = f2bf(v.y); o.z = f2bf(v.z); o.w = f2bf(v.w);
        ((ushort4*)out)[i] = o;
    }
}

// ---------------- bf16 MFMA GEMM: out = A(MxK) * W(NoutxK)^T ----------------
template <int MODE>
__global__ __launch_bounds__(256) void mfma_gemm(
    const u16* __restrict__ A, const u16* __restrict__ W,
    float* __restrict__ outp, const float* __restrict__ bias,
    u16* __restrict__ qkb, u16* __restrict__ vbuf, int K)
{
    __shared__ u16 As[128 * 32];
    __shared__ u16 Ws[128 * 32];
    const int tid = threadIdx.x;
    const int lane = tid & 63, wave = tid >> 6;
    const int g = lane >> 4, c = lane & 15;
    const int wr = wave >> 1, wc = wave & 1;
    const int row0 = blockIdx.y * 128, col0 = blockIdx.x * 128;

    f32x4 acc[4][4];
    #pragma unroll
    for (int m = 0; m < 4; ++m)
        #pragma unroll
        for (int n = 0; n < 4; ++n) acc[m][n] = (f32x4){0.f, 0.f, 0.f, 0.f};

    for (int k0 = 0; k0 < K; k0 += 32) {
        __syncthreads();
        #pragma unroll
        for (int rep = 0; rep < 2; ++rep) {
            const int idx = rep * 256 + tid;
            const int r_ = idx >> 2, ch = idx & 3;
            gload_lds16(A + (size_t)(row0 + r_) * K + k0 + ch * 8,
                        As + rep * 2048 + wave * 512);
            gload_lds16(W + (size_t)(col0 + r_) * K + k0 + ch * 8,
                        Ws + rep * 2048 + wave * 512);
        }
        __syncthreads();

        b16x8 af[4], wf[4];
        #pragma unroll
        for (int m = 0; m < 4; ++m)
            af[m] = *(const b16x8*)&As[(wr * 64 + m * 16 + c) * 32 + g * 8];
        #pragma unroll
        for (int n = 0; n < 4; ++n)
            wf[n] = *(const b16x8*)&Ws[(wc * 64 + n * 16 + c) * 32 + g * 8];
        #pragma unroll
        for (int m = 0; m < 4; ++m)
            #pragma unroll
            for (int n = 0; n < 4; ++n)
                acc[m][n] = MFMA(af[m], wf[n], acc[m][n]);
    }

    #pragma unroll
    for (int m = 0; m < 4; ++m)
        #pragma unroll
        for (int n = 0; n < 4; ++n)
            #pragma unroll
            for (int r = 0; r < 4; ++r) {
                const int row = row0 + wr * 64 + m * 16 + g * 4 + r;
                const int col = col0 + wc * 64 + n * 16 + c;
                const float v = acc[m][n][r];
                if (MODE == 0) {
                    const int which = col >> 10, hd = col & 1023;
                    const int hh = hd >> 6, dd = hd & 63;
                    const int bb = row >> 11, nn = row & (N - 1);
                    if (which < 2)
                        qkb[(size_t)which * (B * H * N * D) +
                            (((size_t)(bb * H + hh)) * N + nn) * 64 + dd] = f2bf(v);
                    else
                        vbuf[(((size_t)(bb * H + hh)) * N + nn) * 64 + dd] = f2bf(v);
                } else {
                    outp[(size_t)row * C + col] = v + bias[col];
                }
            }
}

// ---------------- fused LayerNorm(D=64) + RoPE on q,k rows (bf16 io) -------
// Q pre-scaled by D^-0.5 * log2(e)  (exp2-domain softmax)
__global__ __launch_bounds__(256) void lnrope_kernel(
    u16* __restrict__ qkv, const float* __restrict__ qw, const float* __restrict__ qb,
    const float* __restrict__ kw, const float* __restrict__ kb, const int* __restrict__ pos)
{
    const int tid = threadIdx.x;
    const int lane = tid & 63;
    const int row = blockIdx.x * 4 + (tid >> 6);
    const int isK = row >= (B * H * N);
    const float* w = isK ? kw : qb - 0;  // placeholder avoided below
    const float* wsel = isK ? kw : qw;
    const float* bsel = isK ? kb : qb;
    u16* rowp = qkv + (size_t)row * D;

    float v = bf2f(rowp[lane]);
    float s = v;
    #pragma unroll
    for (int msk = 32; msk >= 1; msk >>= 1) s += __shfl_xor(s, msk, 64);
    const float mu = s * (1.0f / 64.0f);
    const float dv = v - mu;
    float s2 = dv * dv;
    #pragma unroll
    for (int msk = 32; msk >= 1; msk >>= 1) s2 += __shfl_xor(s2, msk, 64);
    const float var = s2 * (1.0f / 64.0f);
    float y = dv * rsqrtf(var + LN_EPS) * wsel[lane] + bsel[lane];
    (void)w;

    const int n = row & (N - 1);
    const int d2 = lane & 31;
    const float inv_freq = 1.0f / powf(10000.0f, (float)d2 * (1.0f / 32.0f));
    const float ang = (float)pos[n] * inv_freq;
    const float cc = cosf(ang), sn = sinf(ang);
    const float partner = __shfl_xor(y, 32, 64);
    float outv;
    if (lane < 32) outv = y * cc - partner * sn;
    else           outv = partner * sn + y * cc;
    if (!isK) outv *= 0.18033688011112042f;   // 0.125 * log2(e)
    rowp[lane] = f2bf(outv);
}

// ---------------- attention: bf16 MFMA, swapped QK^T, exp2 online softmax ---
// 256 thr = 4 waves; q-tile 128 (32 q/wave as 2 q-blocks); KVBLK 64; dbuf LDS.
__global__ __launch_bounds__(256) void attn_kernel(
    const u16* __restrict__ qkb, const u16* __restrict__ vb, u16* __restrict__ aout)
{
    __shared__ u16 Kl[2][64 * 64];   // [j][d], 16B chunks XOR-swizzled by (j&7)
    __shared__ u16 Vt[2][64 * 64];   // bijection-matched transposed V (see notes)
    const int tid = threadIdx.x, lane = tid & 63, wave = tid >> 6;
    const int g = lane >> 4, c = lane & 15;
    const int p_ = blockIdx.x;                       // 512 blocks
    const int bid = (p_ & 7) * 64 + (p_ >> 3);       // XCD-contiguous heads
    const int qt = bid & 15, h = (bid >> 4) & 15, b = bid >> 8;
    const size_t headbase = ((size_t)(b * H + h)) * N * D;
    const u16* Qg = qkb + headbase;
    const u16* Kg = qkb + (size_t)(B * H * N * D) + headbase;
    const u16* Vg = vb + headbase;
    const int q0 = qt * 128 + wave * 32;

    b16x8 qf[2][2];
    #pragma unroll
    for (int qb_ = 0; qb_ < 2; ++qb_)
        #pragma unroll
        for (int ks = 0; ks < 2; ++ks)
            qf[qb_][ks] = *(const b16x8*)&Qg[(size_t)(q0 + qb_ * 16 + c) * 64 + ks * 32 + g * 8];

    f32x4 oacc[2][4];
    #pragma unroll
    for (int qb_ = 0; qb_ < 2; ++qb_)
        #pragma unroll
        for (int nd = 0; nd < 4; ++nd) oacc[qb_][nd] = (f32x4){0.f, 0.f, 0.f, 0.f};
    float m_run[2] = {-1e30f, -1e30f}, l_run[2] = {0.f, 0.f};

    // V staging ids: thread owns rows jp, jp+1, d-chunk dg
    const int jp = (tid & 31) * 2, dg = tid >> 5;
    const int vchunk = 4 * (jp >> 5) + ((jp >> 2) & 3);   // 4k+g
    const int vlow = 4 * ((jp >> 4) & 1) + (jp & 3);      // 4a+s

    auto stageK = [&](int kt, int bi) {
        #pragma unroll
        for (int rep = 0; rep < 2; ++rep) {
            const int idx = rep * 256 + tid;
            const int j = idx >> 3, cc = idx & 7;
            const int cg = cc ^ (j & 7);
            gload_lds16(Kg + (size_t)(kt * 64 + j) * 64 + cg * 8,
                        (u16*)Kl[bi] + rep * 2048 + wave * 512);
        }
    };

    b16x8 vA, vB;
    auto loadV = [&](int kt) {
        vA = *(const b16x8*)&Vg[(size_t)(kt * 64 + jp) * 64 + dg * 8];
        vB = *(const b16x8*)&Vg[(size_t)(kt * 64 + jp + 1) * 64 + dg * 8];
    };
    auto writeV = [&](int bi) {
        #pragma unroll
        for (int dd = 0; dd < 8; ++dd) {
            const u32 pk = (u32)(u16)vA[dd] | ((u32)(u16)vB[dd] << 16);
            *(u32*)((u16*)Vt[bi] + (dg * 8 + dd) * 64 + ((vchunk ^ dd) << 3) + vlow) = pk;
        }
    };

    auto softmax_qb = [&](f32x4 (&s)[4], int qb_, PW (&pwk)[2]) {
        float pm = s[0][0];
        #pragma unroll
        for (int jt = 0; jt < 4; ++jt)
            #pragma unroll
            for (int r = 0; r < 4; ++r) pm = fmaxf(pm, s[jt][r]);
        pm = fmaxf(pm, __shfl_xor(pm, 16, 64));
        pm = fmaxf(pm, __shfl_xor(pm, 32, 64));
        if (__any(pm > m_run[qb_] + 8.0f)) {          // T13 defer-max
            const float mnew = fmaxf(m_run[qb_], pm);
            const float fs = exp2_asm(m_run[qb_] - mnew);
            l_run[qb_] *= fs;
            #pragma unroll
            for (int r = 0; r < 4; ++r) {
                const float fr = __shfl(fs, (lane & 48) + g * 4 + r, 64);
                #pragma unroll
                for (int nd = 0; nd < 4; ++nd) oacc[qb_][nd][r] *= fr;
            }
            m_run[qb_] = mnew;
        }
        float ps = 0.f;
        #pragma unroll
        for (int jt = 0; jt < 4; ++jt)
            #pragma unroll
            for (int r = 0; r < 4; ++r) {
                const float pv = exp2_asm(s[jt][r] - m_run[qb_]);
                s[jt][r] = pv;
                ps += pv;
            }
        ps += __shfl_xor(ps, 16, 64);
        ps += __shfl_xor(ps, 32, 64);
        l_run[qb_] += ps;
        #pragma unroll
        for (int ks = 0; ks < 2; ++ks)
            #pragma unroll
            for (int wd = 0; wd < 4; ++wd)
                pwk[ks].w[wd] = cvtpk_bf16(s[2 * ks + (wd >> 1)][2 * (wd & 1)],
                                           s[2 * ks + (wd >> 1)][2 * (wd & 1) + 1]);
    };

    auto compute = [&](int bi) {
        const char* Kb = (const char*)Kl[bi];
        const char* Vb = (const char*)Vt[bi];
        f32x4 s0[4], s1[4];
        #pragma unroll
        for (int jt = 0; jt < 4; ++jt) {
            s0[jt] = (f32x4){0.f, 0.f, 0.f, 0.f};
            s1[jt] = (f32x4){0.f, 0.f, 0.f, 0.f};
        }
        #pragma unroll
        for (int jt = 0; jt < 4; ++jt)
            #pragma unroll
            for (int ks = 0; ks < 2; ++ks) {
                const int byteoff = (jt * 16 + c) * 128 + ((ks * 64 + g * 16) ^ ((c & 7) << 4));
                const b16x8 kf = *(const b16x8*)(Kb + byteoff);
                s0[jt] = MFMA(kf, qf[0][ks], s0[jt]);
                s1[jt] = MFMA(kf, qf[1][ks], s1[jt]);
            }
        PW pw0[2], pw1[2];
        softmax_qb(s0, 0, pw0);
        softmax_qb(s1, 1, pw1);
        #pragma unroll
        for (int nd = 0; nd < 4; ++nd) {
            const int rowb = (nd * 16 + c) * 128;
            #pragma unroll
            for (int ks = 0; ks < 2; ++ks) {
                const b16x8 vf = *(const b16x8*)(Vb + rowb + (((4 * ks + g) ^ (c & 7)) << 4));
                oacc[0][nd] = MFMA(pw0[ks].v, vf, oacc[0][nd]);
                oacc[1][nd] = MFMA(pw1[ks].v, vf, oacc[1][nd]);
            }
        }
    };

    // prologue: stage tile 0 into buf 0
    stageK(0, 0);
    loadV(0);
    writeV(0);
    __syncthreads();

    for (int kt = 0; kt < N / 64 - 1; ++kt) {
        const int bi = kt & 1;
        loadV(kt + 1);             // T14: issue global V loads early
        stageK(kt + 1, bi ^ 1);    // async K stage into other buffer
        compute(bi);
        writeV(bi ^ 1);            // lands after compute; barrier drains rest
        __syncthreads();
    }
    compute((N / 64 - 1) & 1);

    #pragma unroll
    for (int qb_ = 0; qb_ < 2; ++qb_) {
        const float linv = 1.0f / l_run[qb_];
        #pragma unroll
        for (int r = 0; r < 4; ++r) {
            const float li = __shfl(linv, (lane & 48) + g * 4 + r, 64);
            const int n_ = q0 + qb_ * 16 + g * 4 + r;
            #pragma unroll
            for (int nd = 0; nd < 4; ++nd)
                aout[((size_t)(b * N + n_)) * C + h * 64 + nd * 16 + c] =
                    f2bf(oacc[qb_][nd][r] * li);
        }
    }
}

extern "C" void kernel_launch(void* const* d_in, const int* in_sizes, int n_in,
                              void* d_out, int out_size, void* d_ws, size_t ws_size,
                              hipStream_t stream) {
    const float* x      = (const float*)d_in[0];
    const float* qkv_w  = (const float*)d_in[1];
    const float* qn_w   = (const float*)d_in[2];
    const float* qn_b   = (const float*)d_in[3];
    const float* kn_w   = (const float*)d_in[4];
    const float* kn_b   = (const float*)d_in[5];
    const float* proj_w = (const float*)d_in[6];
    const float* proj_b = (const float*)d_in[7];
    const int*   pos    = (const int*)d_in[8];
    float* out = (float*)d_out;

    u16* xb     = (u16*)d_ws;                 // 4096x1024
    u16* wqkvb  = xb + 4194304;               // 3072x1024
    u16* wprojb = wqkvb + 3145728;            // 1024x1024
    u16* qkb    = wprojb + 1048576;           // [2][B][H][N][D]
    u16* vbuf   = qkb + 8388608;              // [B][H][N][D]
    u16* aob    = vbuf + 4194304;             // [B][N][C]

    castk<<<4096, 256, 0, stream>>>(x, xb, 1048576);
    castk<<<3072, 256, 0, stream>>>(qkv_w, wqkvb, 786432);
    castk<<<1024, 256, 0, stream>>>(proj_w, wprojb, 262144);

    mfma_gemm<0><<<dim3(24, 32), 256, 0, stream>>>(xb, wqkvb, nullptr, nullptr, qkb, vbuf, C);
    lnrope_kernel<<<32768, 256, 0, stream>>>(qkb, qn_w, qn_b, kn_w, kn_b, pos);
    attn_kernel<<<512, 256, 0, stream>>>(qkb, vbuf, aob);
    mfma_gemm<1><<<dim3(8, 32), 256, 0, stream>>>(aob, wprojb, out, proj_b, nullptr, nullptr, C);
}

// Round 5
// 145.972 us; speedup vs baseline: 10.8681x; 1.2258x over previous
//
#include <hip/hip_runtime.h>
#include <hip/hip_bf16.h>
#include <math.h>
#include <stdint.h>

#define B 2
#define N 2048
#define C 1024
#define H 16
#define D 64
#define LN_EPS 1e-5f

typedef unsigned short u16;
typedef unsigned int u32;
typedef __attribute__((ext_vector_type(8))) short b16x8;
typedef __attribute__((ext_vector_type(4))) float f32x4;

#define MFMA(a, b, c) __builtin_amdgcn_mfma_f32_16x16x32_bf16(a, b, c, 0, 0, 0)

__device__ __forceinline__ u16 f2bf(float x) {
    u32 u = __float_as_uint(x);
    u32 r = u + 0x7fff + ((u >> 16) & 1);   // RNE
    return (u16)(r >> 16);
}
__device__ __forceinline__ float bf2f(u16 v) {
    return __uint_as_float(((u32)v) << 16);
}
__device__ __forceinline__ void gload_lds16(const void* g, void* l) {
    __builtin_amdgcn_global_load_lds(
        (__attribute__((address_space(1))) void*)(uintptr_t)g,
        (__attribute__((address_space(3))) void*)l, 16, 0, 0);
}
__device__ __forceinline__ float exp2_asm(float x) {
    float r;
    asm("v_exp_f32 %0, %1" : "=v"(r) : "v"(x));
    return r;
}
__device__ __forceinline__ u32 cvtpk_bf16(float lo, float hi) {
    u32 r;
    asm("v_cvt_pk_bf16_f32 %0, %1, %2" : "=v"(r) : "v"(lo), "v"(hi));
    return r;
}

union PW { u32 w[4]; b16x8 v; };

// ---------------- fused cast fp32 -> bf16 for x, qkv_w, proj_w --------------
__global__ __launch_bounds__(256) void castk3(
    const float* __restrict__ a, u16* __restrict__ oa, int na4,
    const float* __restrict__ b, u16* __restrict__ ob, int nb4,
    const float* __restrict__ c, u16* __restrict__ oc, int nc4)
{
    int i = blockIdx.x * 256 + threadIdx.x;
    const float* src; u16* dst; int off;
    if (i < na4) { src = a; dst = oa; off = i; }
    else if (i < na4 + nb4) { src = b; dst = ob; off = i - na4; }
    else if (i < na4 + nb4 + nc4) { src = c; dst = oc; off = i - na4 - nb4; }
    else return;
    float4 v = ((const float4*)src)[off];
    ushort4 o;
    o.x = f2bf(v.x); o.y = f2bf(v.y); o.z = f2bf(v.z); o.w = f2bf(v.w);
    ((ushort4*)dst)[off] = o;
}

// ---------------- bf16 MFMA GEMM, 2-phase dbuf: out = A(MxK) * W(NoutxK)^T --
// BM=128, BN=32*NFR, BK=32. 4 waves 2x2. MODE 0: scatter qkv; MODE 1: f32+bias
template <int MODE, int NFR>
__global__ __launch_bounds__(256) void mfma_gemm(
    const u16* __restrict__ A, const u16* __restrict__ W,
    float* __restrict__ outp, const float* __restrict__ bias,
    u16* __restrict__ qkb, u16* __restrict__ vbuf, int K)
{
    __shared__ u16 As[2][128 * 32];
    __shared__ u16 Ws[2][1024 * NFR];
    const int tid = threadIdx.x;
    const int lane = tid & 63, wave = tid >> 6;
    const int g = lane >> 4, c = lane & 15;
    const int wr = wave >> 1, wc = wave & 1;
    const int row0 = blockIdx.y * 128, col0 = blockIdx.x * (32 * NFR);

    f32x4 acc[4][NFR];
    #pragma unroll
    for (int m = 0; m < 4; ++m)
        #pragma unroll
        for (int n = 0; n < NFR; ++n) acc[m][n] = (f32x4){0.f, 0.f, 0.f, 0.f};

    auto stage = [&](int k0, int bi) {
        #pragma unroll
        for (int rep = 0; rep < 2; ++rep) {
            const int idx = rep * 256 + tid;
            const int r_ = idx >> 2, ch = idx & 3;
            gload_lds16(A + (size_t)(row0 + r_) * K + k0 + ch * 8,
                        As[bi] + rep * 2048 + wave * 512);
        }
        #pragma unroll
        for (int rep = 0; rep < NFR / 2; ++rep) {
            const int idx = rep * 256 + tid;
            const int r_ = idx >> 2, ch = idx & 3;
            gload_lds16(W + (size_t)(col0 + r_) * K + k0 + ch * 8,
                        Ws[bi] + rep * 2048 + wave * 512);
        }
    };

    stage(0, 0);
    __syncthreads();
    const int nt = K / 32;
    for (int t = 0; t < nt; ++t) {
        const int bi = t & 1;
        if (t + 1 < nt) stage((t + 1) * 32, bi ^ 1);

        b16x8 af[4], wf[NFR];
        #pragma unroll
        for (int m = 0; m < 4; ++m)
            af[m] = *(const b16x8*)&As[bi][(wr * 64 + m * 16 + c) * 32 + g * 8];
        #pragma unroll
        for (int n = 0; n < NFR; ++n)
            wf[n] = *(const b16x8*)&Ws[bi][(wc * 16 * NFR + n * 16 + c) * 32 + g * 8];
        #pragma unroll
        for (int m = 0; m < 4; ++m)
            #pragma unroll
            for (int n = 0; n < NFR; ++n)
                acc[m][n] = MFMA(af[m], wf[n], acc[m][n]);
        __syncthreads();
    }

    #pragma unroll
    for (int m = 0; m < 4; ++m)
        #pragma unroll
        for (int n = 0; n < NFR; ++n)
            #pragma unroll
            for (int r = 0; r < 4; ++r) {
                const int row = row0 + wr * 64 + m * 16 + g * 4 + r;
                const int col = col0 + wc * 16 * NFR + n * 16 + c;
                const float v = acc[m][n][r];
                if (MODE == 0) {
                    const int which = col >> 10, hd = col & 1023;
                    const int hh = hd >> 6, dd = hd & 63;
                    const int bb = row >> 11, nn = row & (N - 1);
                    if (which < 2)
                        qkb[(size_t)which * (B * H * N * D) +
                            (((size_t)(bb * H + hh)) * N + nn) * 64 + dd] = f2bf(v);
                    else
                        vbuf[(((size_t)(bb * H + hh)) * N + nn) * 64 + dd] = f2bf(v);
                } else {
                    outp[(size_t)row * C + col] = v + bias[col];
                }
            }
}

// ---------------- fused LayerNorm(D=64) + RoPE on q,k rows (bf16 io) -------
// Q pre-scaled by D^-0.5 * log2(e)  (exp2-domain softmax)
__global__ __launch_bounds__(256) void lnrope_kernel(
    u16* __restrict__ qkv, const float* __restrict__ qw, const float* __restrict__ qb,
    const float* __restrict__ kw, const float* __restrict__ kb, const int* __restrict__ pos)
{
    const int tid = threadIdx.x;
    const int lane = tid & 63;
    const int row = blockIdx.x * 4 + (tid >> 6);
    const int isK = row >= (B * H * N);
    const float* wsel = isK ? kw : qw;
    const float* bsel = isK ? kb : qb;
    u16* rowp = qkv + (size_t)row * D;

    float v = bf2f(rowp[lane]);
    float s = v;
    #pragma unroll
    for (int msk = 32; msk >= 1; msk >>= 1) s += __shfl_xor(s, msk, 64);
    const float mu = s * (1.0f / 64.0f);
    const float dv = v - mu;
    float s2 = dv * dv;
    #pragma unroll
    for (int msk = 32; msk >= 1; msk >>= 1) s2 += __shfl_xor(s2, msk, 64);
    const float var = s2 * (1.0f / 64.0f);
    float y = dv * rsqrtf(var + LN_EPS) * wsel[lane] + bsel[lane];

    const int n = row & (N - 1);
    const int d2 = lane & 31;
    // inv_freq = 10000^(-d2/32) = 2^(-d2 * log2(10000)/32)
    const float inv_freq = exp2_asm((float)d2 * -0.41524101186092029f);
    const float ang = (float)pos[n] * inv_freq;
    const float cc = cosf(ang), sn = sinf(ang);
    const float partner = __shfl_xor(y, 32, 64);
    float outv;
    if (lane < 32) outv = y * cc - partner * sn;
    else           outv = partner * sn + y * cc;
    if (!isK) outv *= 0.18033688011112042f;   // 0.125 * log2(e)
    rowp[lane] = f2bf(outv);
}

// ---------------- attention: 8 waves x 16 q-rows, q-tile 128, KVBLK 64 ------
__global__ __launch_bounds__(512, 4) void attn_kernel(
    const u16* __restrict__ qkb, const u16* __restrict__ vb, u16* __restrict__ aout)
{
    __shared__ u16 Kl[2][64 * 64];   // [j][d], 16B chunks XOR-swizzled by (j&7)
    __shared__ u16 Vt[2][64 * 64];   // [d][j-slot], group 4*j5+j32 ^ (d&7), pos 4*j4+j10
    const int tid = threadIdx.x, lane = tid & 63, wave = tid >> 6;
    const int g = lane >> 4, c = lane & 15;
    const int p_ = blockIdx.x;                       // 512 blocks
    const int bid = (p_ & 7) * 64 + (p_ >> 3);       // XCD-contiguous heads
    const int qt = bid & 15, h = (bid >> 4) & 15, b = bid >> 8;
    const size_t headbase = ((size_t)(b * H + h)) * N * D;
    const u16* Qg = qkb + headbase;
    const u16* Kg = qkb + (size_t)(B * H * N * D) + headbase;
    const u16* Vg = vb + headbase;
    const int q0 = qt * 128 + wave * 16;

    b16x8 qf[2];
    #pragma unroll
    for (int ks = 0; ks < 2; ++ks)
        qf[ks] = *(const b16x8*)&Qg[(size_t)(q0 + c) * 64 + ks * 32 + g * 8];

    f32x4 oacc[4];
    #pragma unroll
    for (int nd = 0; nd < 4; ++nd) oacc[nd] = (f32x4){0.f, 0.f, 0.f, 0.f};
    float m_run = -1e30f, l_run = 0.f;

    // --- K staging: 512 x 16B, source pre-swizzled, LDS linear ---
    auto stageK = [&](int kt, int bi) {
        const int j = tid >> 3, cc2 = tid & 7;
        const int cg = cc2 ^ (j & 7);
        gload_lds16(Kg + (size_t)(kt * 64 + j) * 64 + cg * 8,
                    (u16*)Kl[bi] + (size_t)tid * 8);
    };

    // --- V staging: thread owns rows (vjp, vjp+1), d-chunk vdg, dd-half vddh
    // bijection (matches PV read k-order): group = 4*j[5]+j[3:2], pos = 4*j[4]+j[1:0]
    const int vjp = (tid & 31) * 2;
    const int vdg = (tid >> 5) & 7;
    const int vddh = tid >> 8;
    const int vchunk = 4 * (vjp >> 5) + ((vjp >> 2) & 3);
    const int vlow = 4 * ((vjp >> 4) & 1) + (vjp & 3);
    ushort4 vA4, vB4;
    auto loadV = [&](int kt) {
        vA4 = *(const ushort4*)&Vg[(size_t)(kt * 64 + vjp) * 64 + vdg * 8 + vddh * 4];
        vB4 = *(const ushort4*)&Vg[(size_t)(kt * 64 + vjp + 1) * 64 + vdg * 8 + vddh * 4];
    };
    auto writeV = [&](int bi) {
        const u16 a_[4] = {vA4.x, vA4.y, vA4.z, vA4.w};
        const u16 b_[4] = {vB4.x, vB4.y, vB4.z, vB4.w};
        #pragma unroll
        for (int i = 0; i < 4; ++i) {
            const int dd = vddh * 4 + i;
            const int d = vdg * 8 + dd;
            const u32 pk = (u32)a_[i] | ((u32)b_[i] << 16);
            *(u32*)&Vt[bi][d * 64 + ((vchunk ^ dd) << 3) + vlow] = pk;
        }
    };

    auto compute = [&](int bi) {
        const char* Kb = (const char*)Kl[bi];
        const u16* Vb = Vt[bi];
        f32x4 s[4];
        #pragma unroll
        for (int jt = 0; jt < 4; ++jt) s[jt] = (f32x4){0.f, 0.f, 0.f, 0.f};
        __builtin_amdgcn_s_setprio(1);
        #pragma unroll
        for (int jt = 0; jt < 4; ++jt)
            #pragma unroll
            for (int ks = 0; ks < 2; ++ks) {
                const int byteoff = (jt * 16 + c) * 128 + ((ks * 64 + g * 16) ^ ((c & 7) << 4));
                const b16x8 kf = *(const b16x8*)(Kb + byteoff);
                s[jt] = MFMA(kf, qf[ks], s[jt]);
            }
        __builtin_amdgcn_s_setprio(0);

        float pm = s[0][0];
        #pragma unroll
        for (int jt = 0; jt < 4; ++jt)
            #pragma unroll
            for (int r = 0; r < 4; ++r) pm = fmaxf(pm, s[jt][r]);
        pm = fmaxf(pm, __shfl_xor(pm, 16, 64));
        pm = fmaxf(pm, __shfl_xor(pm, 32, 64));
        if (__any(pm > m_run + 8.0f)) {               // T13 defer-max
            const float mnew = fmaxf(m_run, pm);
            const float fs = exp2_asm(m_run - mnew);
            l_run *= fs;
            #pragma unroll
            for (int r = 0; r < 4; ++r) {
                const float fr = __shfl(fs, (lane & 48) + g * 4 + r, 64);
                #pragma unroll
                for (int nd = 0; nd < 4; ++nd) oacc[nd][r] *= fr;
            }
            m_run = mnew;
        }
        float ps = 0.f;
        #pragma unroll
        for (int jt = 0; jt < 4; ++jt)
            #pragma unroll
            for (int r = 0; r < 4; ++r) {
                const float pv = exp2_asm(s[jt][r] - m_run);
                s[jt][r] = pv;
                ps += pv;
            }
        ps += __shfl_xor(ps, 16, 64);
        ps += __shfl_xor(ps, 32, 64);
        l_run += ps;
        PW pw[2];
        #pragma unroll
        for (int ks = 0; ks < 2; ++ks)
            #pragma unroll
            for (int wd = 0; wd < 4; ++wd)
                pw[ks].w[wd] = cvtpk_bf16(s[2 * ks + (wd >> 1)][2 * (wd & 1)],
                                          s[2 * ks + (wd >> 1)][2 * (wd & 1) + 1]);

        __builtin_amdgcn_s_setprio(1);
        #pragma unroll
        for (int nd = 0; nd < 4; ++nd) {
            #pragma unroll
            for (int ks = 0; ks < 2; ++ks) {
                const b16x8 vf = *(const b16x8*)&Vb[(nd * 16 + c) * 64 +
                                                   (((4 * ks + g) ^ (c & 7)) << 3)];
                oacc[nd] = MFMA(pw[ks].v, vf, oacc[nd]);
            }
        }
        __builtin_amdgcn_s_setprio(0);
    };

    stageK(0, 0);
    loadV(0);
    writeV(0);
    __syncthreads();

    for (int kt = 0; kt < N / 64 - 1; ++kt) {
        const int bi = kt & 1;
        loadV(kt + 1);             // T14: issue global V loads early
        stageK(kt + 1, bi ^ 1);    // async K stage into other buffer
        compute(bi);
        writeV(bi ^ 1);            // after compute; barrier drains the rest
        __syncthreads();
    }
    compute((N / 64 - 1) & 1);

    const float linv = 1.0f / l_run;
    #pragma unroll
    for (int r = 0; r < 4; ++r) {
        const float li = __shfl(linv, (lane & 48) + g * 4 + r, 64);
        const int n_ = q0 + g * 4 + r;
        #pragma unroll
        for (int nd = 0; nd < 4; ++nd)
            aout[((size_t)(b * N + n_)) * C + h * 64 + nd * 16 + c] =
                f2bf(oacc[nd][r] * li);
    }
}

extern "C" void kernel_launch(void* const* d_in, const int* in_sizes, int n_in,
                              void* d_out, int out_size, void* d_ws, size_t ws_size,
                              hipStream_t stream) {
    const float* x      = (const float*)d_in[0];
    const float* qkv_w  = (const float*)d_in[1];
    const float* qn_w   = (const float*)d_in[2];
    const float* qn_b   = (const float*)d_in[3];
    const float* kn_w   = (const float*)d_in[4];
    const float* kn_b   = (const float*)d_in[5];
    const float* proj_w = (const float*)d_in[6];
    const float* proj_b = (const float*)d_in[7];
    const int*   pos    = (const int*)d_in[8];
    float* out = (float*)d_out;

    u16* xb     = (u16*)d_ws;                 // 4096x1024
    u16* wqkvb  = xb + 4194304;               // 3072x1024
    u16* wprojb = wqkvb + 3145728;            // 1024x1024
    u16* qkb    = wprojb + 1048576;           // [2][B][H][N][D]
    u16* vbuf   = qkb + 8388608;              // [B][H][N][D]
    u16* aob    = vbuf + 4194304;             // [B][N][C]

    castk3<<<8192, 256, 0, stream>>>(x, xb, 1048576,
                                     qkv_w, wqkvb, 786432,
                                     proj_w, wprojb, 262144);

    mfma_gemm<0, 4><<<dim3(24, 32), 256, 0, stream>>>(xb, wqkvb, nullptr, nullptr, qkb, vbuf, C);
    lnrope_kernel<<<32768, 256, 0, stream>>>(qkb, qn_w, qn_b, kn_w, kn_b, pos);
    attn_kernel<<<512, 512, 0, stream>>>(qkb, vbuf, aob);
    mfma_gemm<1, 2><<<dim3(16, 32), 256, 0, stream>>>(aob, wprojb, out, proj_b, nullptr, nullptr, C);
}